// Round 2
// baseline (652.086 us; speedup 1.0000x reference)
//
#include <hip/hip_runtime.h>
#include <hip/hip_bf16.h>
#include <math.h>

#define F_IN 512
#define H1   16
#define C2   40

__device__ __forceinline__ float bf2f(unsigned short u) {
  union { unsigned int i; float f; } v; v.i = ((unsigned int)u) << 16; return v.f;
}
__device__ __forceinline__ unsigned short f2bf(float f) {
  __hip_bfloat16 b = __float2bfloat16(f);  // RNE
  return *reinterpret_cast<unsigned short*>(&b);
}

// ---------------- zero degree ----------------
__global__ __launch_bounds__(256) void k_zero(int* deg, int n) {
  int i = blockIdx.x * 256 + threadIdx.x;
  if (i < n) deg[i] = 0;
}

// ---------------- in-degree histogram (int atomics) ----------------
__global__ __launch_bounds__(256) void k_degree(const int* __restrict__ dst, int* deg, int E) {
  int stride = gridDim.x * 256;
  for (int e = blockIdx.x * 256 + threadIdx.x; e < E; e += stride)
    atomicAdd(&deg[dst[e]], 1);
}

// ---------------- scan step 1: per-256-chunk sums ----------------
__global__ __launch_bounds__(256) void k_scan1(const int* __restrict__ deg, int* bsum, int N) {
  __shared__ int lds[256];
  int t = threadIdx.x, i = blockIdx.x * 256 + t;
  lds[t] = (i < N) ? deg[i] : 0;
  __syncthreads();
  for (int off = 128; off; off >>= 1) {
    if (t < off) lds[t] += lds[t + off];
    __syncthreads();
  }
  if (t == 0) bsum[blockIdx.x] = lds[0];
}

// ---------------- scan step 2: exclusive scan of block sums (nb<=512) ----------------
__global__ __launch_bounds__(512) void k_scan2(int* bsum, int nb, int* start, int N, int E) {
  __shared__ int lds[512];
  int t = threadIdx.x;
  int v = (t < nb) ? bsum[t] : 0;
  lds[t] = v;
  __syncthreads();
  for (int off = 1; off < 512; off <<= 1) {
    int add = (t >= off) ? lds[t - off] : 0;
    __syncthreads();
    lds[t] += add;
    __syncthreads();
  }
  if (t < nb) bsum[t] = lds[t] - v;  // exclusive block offset
  if (t == 0) start[N] = E;
}

// ---------------- scan step 3: per-element offsets, cursor init, dinv ----------------
__global__ __launch_bounds__(256) void k_scan3(const int* __restrict__ deg,
                                               const int* __restrict__ bsum,
                                               int* start, int* cursor, float* dinv, int N) {
  __shared__ int lds[256];
  int t = threadIdx.x, i = blockIdx.x * 256 + t;
  int v = (i < N) ? deg[i] : 0;
  lds[t] = v;
  __syncthreads();
  for (int off = 1; off < 256; off <<= 1) {
    int add = (t >= off) ? lds[t - off] : 0;
    __syncthreads();
    lds[t] += add;
    __syncthreads();
  }
  if (i < N) {
    int excl = bsum[blockIdx.x] + lds[t] - v;
    start[i] = excl;
    cursor[i] = excl;
    dinv[i] = rsqrtf((float)(v + 1));
  }
}

// ---------------- CSR bucket fill (int atomics on cursors) ----------------
__global__ __launch_bounds__(256) void k_fill(const int* __restrict__ src,
                                              const int* __restrict__ dst,
                                              int* cursor, int* csr, int E) {
  int stride = gridDim.x * 256;
  for (int e = blockIdx.x * 256 + threadIdx.x; e < E; e += stride) {
    int d = dst[e];
    int pos = atomicAdd(&cursor[d], 1);
    csr[pos] = src[e];
  }
}

// ---------------- g1 = bf16( (x @ W1) * dinv[row] ) ----------------
// One wave per row (grid-stride). Lane l: coalesced load of x[row][8l..8l+8),
// W slice W1[8l..8l+8)[0..16) held in 128 registers (loaded once/wave),
// 128 FMAs, then 6-step reduce-scatter butterfly -> lane l holds class l&15.
__global__ __launch_bounds__(256, 2) void k_gemm1(const float* __restrict__ x,
                                                  const float* __restrict__ W1,
                                                  const float* __restrict__ dinv,
                                                  unsigned short* __restrict__ g1bf, int N) {
  int lane = threadIdx.x & 63;
  int wid = (int)((blockIdx.x * (long long)blockDim.x + threadIdx.x) >> 6);
  int nw = (gridDim.x * blockDim.x) >> 6;

  float wr[128];
#pragma unroll
  for (int j = 0; j < 8; j++) {
    const float* wrow = &W1[(lane * 8 + j) * H1];
    float4 w0 = *(const float4*)&wrow[0];
    float4 w1 = *(const float4*)&wrow[4];
    float4 w2 = *(const float4*)&wrow[8];
    float4 w3 = *(const float4*)&wrow[12];
    wr[j*16+ 0]=w0.x; wr[j*16+ 1]=w0.y; wr[j*16+ 2]=w0.z; wr[j*16+ 3]=w0.w;
    wr[j*16+ 4]=w1.x; wr[j*16+ 5]=w1.y; wr[j*16+ 6]=w1.z; wr[j*16+ 7]=w1.w;
    wr[j*16+ 8]=w2.x; wr[j*16+ 9]=w2.y; wr[j*16+10]=w2.z; wr[j*16+11]=w2.w;
    wr[j*16+12]=w3.x; wr[j*16+13]=w3.y; wr[j*16+14]=w3.z; wr[j*16+15]=w3.w;
  }

  for (int row = wid; row < N; row += nw) {
    const float4* xr = (const float4*)(x + (size_t)row * F_IN);
    float4 a = xr[lane * 2];
    float4 b = xr[lane * 2 + 1];
    float xv[8] = {a.x, a.y, a.z, a.w, b.x, b.y, b.z, b.w};
    float acc[16];
#pragma unroll
    for (int c = 0; c < 16; c++) acc[c] = 0.f;
#pragma unroll
    for (int j = 0; j < 8; j++)
#pragma unroll
      for (int c = 0; c < 16; c++) acc[c] = fmaf(xv[j], wr[j * 16 + c], acc[c]);

    // reduce-scatter: after step s, lane keeps classes whose bit s == lane bit s
    float v8[8];
#pragma unroll
    for (int i = 0; i < 8; i++) {
      float t0 = acc[2*i]   + __shfl_xor(acc[2*i],   1, 64);
      float t1 = acc[2*i+1] + __shfl_xor(acc[2*i+1], 1, 64);
      v8[i] = (lane & 1) ? t1 : t0;
    }
    float v4[4];
#pragma unroll
    for (int i = 0; i < 4; i++) {
      float t0 = v8[2*i]   + __shfl_xor(v8[2*i],   2, 64);
      float t1 = v8[2*i+1] + __shfl_xor(v8[2*i+1], 2, 64);
      v4[i] = ((lane >> 1) & 1) ? t1 : t0;
    }
    float v2[2];
#pragma unroll
    for (int i = 0; i < 2; i++) {
      float t0 = v4[2*i]   + __shfl_xor(v4[2*i],   4, 64);
      float t1 = v4[2*i+1] + __shfl_xor(v4[2*i+1], 4, 64);
      v2[i] = ((lane >> 2) & 1) ? t1 : t0;
    }
    float t0 = v2[0] + __shfl_xor(v2[0], 8, 64);
    float t1 = v2[1] + __shfl_xor(v2[1], 8, 64);
    float v1 = ((lane >> 3) & 1) ? t1 : t0;
    v1 += __shfl_xor(v1, 16, 64);
    v1 += __shfl_xor(v1, 32, 64);

    if (lane < 16) g1bf[row * H1 + lane] = f2bf(v1 * dinv[row]);
  }
}

// ---------------- layer-1 aggregate + relu, fused (wave per node) ----------------
// lane: j = lane&15 (feature), slot = lane>>4 (edge slot, 4-way)
__global__ __launch_bounds__(256) void k_agg1(const int* __restrict__ csr,
                                              const int* __restrict__ start,
                                              const unsigned short* __restrict__ g1bf,
                                              const float* __restrict__ dinv,
                                              const float* __restrict__ b1,
                                              unsigned short* __restrict__ g2bf, int N) {
  int t = threadIdx.x;
  int lane = t & 63;
  int node = (int)((blockIdx.x * (long long)blockDim.x + t) >> 6);
  if (node >= N) return;
  int j = lane & 15, slot = lane >> 4;
  int s0 = start[node], s1 = start[node + 1];
  float acc = 0.f;
  for (int e = s0 + slot; e < s1; e += 4) {
    int s = csr[e];
    acc += bf2f(g1bf[s * H1 + j]);
  }
  acc += __shfl_xor(acc, 16, 64);
  acc += __shfl_xor(acc, 32, 64);
  float di = dinv[node];
  float v = di * (acc + bf2f(g1bf[node * H1 + j])) + b1[j];
  v = fmaxf(v, 0.f) * di;  // relu then pre-scale for layer-2 message
  if (lane < 16) g2bf[node * H1 + lane] = f2bf(v);
}

// ---------------- layer-2 aggregate + W2 + bias + log_softmax, fused ----------------
__global__ __launch_bounds__(256) void k_agg2(const int* __restrict__ csr,
                                              const int* __restrict__ start,
                                              const unsigned short* __restrict__ g2bf,
                                              const float* __restrict__ dinv,
                                              const float* __restrict__ W2,
                                              const float* __restrict__ b2,
                                              float* __restrict__ out, int N) {
  __shared__ float w2s[H1 * C2];
  __shared__ float b2s[C2];
  int t = threadIdx.x;
  for (int i = t; i < H1 * C2; i += 256) w2s[i] = W2[i];
  if (t < C2) b2s[t] = b2[t];
  __syncthreads();

  int lane = t & 63;
  int node = (int)((blockIdx.x * (long long)blockDim.x + t) >> 6);
  if (node >= N) return;
  int j = lane & 15, slot = lane >> 4;
  int s0 = start[node], s1 = start[node + 1];
  float acc = 0.f;
  for (int e = s0 + slot; e < s1; e += 4) {
    int s = csr[e];
    acc += bf2f(g2bf[s * H1 + j]);
  }
  acc += __shfl_xor(acc, 16, 64);
  acc += __shfl_xor(acc, 32, 64);
  float di = dinv[node];
  float s2 = di * (acc + bf2f(g2bf[node * H1 + j]));  // every lane: feature j

  int cl = (lane < C2) ? lane : 0;
  float z = b2s[cl];
#pragma unroll
  for (int jj = 0; jj < H1; jj++) {
    float sj = __shfl(s2, jj, 64);  // broadcast feature jj (held by lane jj)
    z = fmaf(sj, w2s[jj * C2 + cl], z);
  }
  if (lane >= C2) z = -INFINITY;
  float m = z;
#pragma unroll
  for (int off = 32; off; off >>= 1) m = fmaxf(m, __shfl_xor(m, off, 64));
  float p = (lane < C2) ? expf(z - m) : 0.f;
  float ssum = p;
#pragma unroll
  for (int off = 32; off; off >>= 1) ssum += __shfl_xor(ssum, off, 64);
  if (lane < C2) out[(size_t)node * C2 + lane] = z - m - logf(ssum);
}

extern "C" void kernel_launch(void* const* d_in, const int* in_sizes, int n_in,
                              void* d_out, int out_size, void* d_ws, size_t ws_size,
                              hipStream_t stream) {
  const float* x  = (const float*)d_in[0];
  const int*   ei = (const int*)d_in[1];
  const float* W1 = (const float*)d_in[2];
  const float* b1 = (const float*)d_in[3];
  const float* W2 = (const float*)d_in[4];
  const float* b2 = (const float*)d_in[5];
  float* out = (float*)d_out;

  int N = in_sizes[0] / F_IN;
  int E = in_sizes[1] / 2;
  const int* src = ei;
  const int* dst = ei + E;
  int nb = (N + 255) / 256;  // 391 for N=100000 (must be <= 512)

  // workspace layout (byte offsets, 256B-aligned)
  char* w = (char*)d_ws;
  size_t off = 0;
  auto alloc = [&](size_t bytes) { char* p = w + off; off = (off + bytes + 255) & ~(size_t)255; return p; };
  int*   deg    = (int*)alloc((size_t)N * 4);
  int*   start  = (int*)alloc((size_t)(N + 1) * 4);
  int*   cursor = (int*)alloc((size_t)N * 4);
  int*   bsum   = (int*)alloc(512 * 4);
  float* dinv   = (float*)alloc((size_t)N * 4);
  int*   csr    = (int*)alloc((size_t)E * 4);
  unsigned short* g1bf = (unsigned short*)alloc((size_t)N * H1 * 2);
  unsigned short* g2bf = (unsigned short*)alloc((size_t)N * H1 * 2);

  k_zero  <<<nb, 256, 0, stream>>>(deg, N);
  k_degree<<<4096, 256, 0, stream>>>(dst, deg, E);
  k_scan1 <<<nb, 256, 0, stream>>>(deg, bsum, N);
  k_scan2 <<<1, 512, 0, stream>>>(bsum, nb, start, N, E);
  k_scan3 <<<nb, 256, 0, stream>>>(deg, bsum, start, cursor, dinv, N);
  k_fill  <<<4096, 256, 0, stream>>>(src, dst, cursor, csr, E);
  k_gemm1 <<<1024, 256, 0, stream>>>(x, W1, dinv, g1bf, N);
  int aggBlocks = (N * 64 + 255) / 256;
  k_agg1  <<<aggBlocks, 256, 0, stream>>>(csr, start, g1bf, dinv, b1, g2bf, N);
  k_agg2  <<<aggBlocks, 256, 0, stream>>>(csr, start, g2bf, dinv, W2, b2, out, N);
}